// Round 11
// baseline (99.627 us; speedup 1.0000x reference)
//
#include <hip/hip_runtime.h>

#define BB 32
#define NN 4096
#define NQ 8
#define DD 64
#define DV 64
#define CHUNKS 8
#define TOK_PER_BLOCK (NN / CHUNKS)      // 512
#define NWAVES 8                         // 512-thread blocks
#define TOK_PER_WAVE (TOK_PER_BLOCK / NWAVES) // 64
#define NGROUP (TOK_PER_WAVE / 8)        // 8 groups of 8 tokens

// DPP cross-lane add on the VALU pipe (no DS instruction, ~2-4 cyc latency).
template <int CTRL>
__device__ __forceinline__ float dpp_add(float x) {
    union { float f; int i; } in, out;
    in.f = x;
    out.i = __builtin_amdgcn_update_dpp(0, in.i, CTRL, 0xF, 0xF, true);
    return x + out.f;
}
// lane ^ 16 via ds_swizzle BitMode (within 32-lane halves: exact xor16)
__device__ __forceinline__ float swz16_add(float x) {
    union { float f; int i; } in, out;
    in.f = x;
    out.i = __builtin_amdgcn_ds_swizzle(in.i, 0x401F);
    return x + out.f;
}

// R11 = R10's winning per-wave structure (depth-3 quad-buffered prefetch,
// DPP g-reduction, in-register softmax, ~220 VGPR / 2 waves-per-SIMD — the
// proven ceiling) consolidated into 512-thread blocks: CHUNKS=8, 256 blocks
// = 1 block/CU, same 8 waves/CU. Halves epilogue instances and partial
// traffic (PU 1MB->0.5MB). Epilogue LDS stores packed as float4.
// DO NOT: re-fuse the final reduce (R8/R9: allocator spills, 16->85us);
// raise min-waves past 2 (R8: spills); shrink per-wave token count (R2/R3:
// TLP doesn't fix per-wave latency, block overhead dominates).
__global__ __launch_bounds__(512, 2) void slot_attn_partial(
    const float* __restrict__ keys, const float* __restrict__ values,
    const float* __restrict__ query, float* __restrict__ PU, float* __restrict__ PS)
{
    const int b     = blockIdx.y;
    const int chnk  = blockIdx.x;
    const int tid   = threadIdx.x;
    const int wave  = tid >> 6;
    const int lane  = tid & 63;
    const int t_sub = lane >> 3;  // token within group (0..7)
    const int g     = lane & 7;   // dim octet (0..7)

    // Q octet g for all 8 slots, pre-scaled by 1/sqrt(64)
    float4 q0[8], q1[8];
    const float* qb = query + (size_t)b * NQ * DD + 8 * g;
#pragma unroll
    for (int m = 0; m < 8; ++m) {
        float4 a = *(const float4*)(qb + m * DD);
        float4 c = *(const float4*)(qb + m * DD + 4);
        a.x *= 0.125f; a.y *= 0.125f; a.z *= 0.125f; a.w *= 0.125f;
        c.x *= 0.125f; c.y *= 0.125f; c.z *= 0.125f; c.w *= 0.125f;
        q0[m] = a; q1[m] = c;
    }

    const int tok0 = chnk * TOK_PER_BLOCK + wave * TOK_PER_WAVE;
    const float* Kbase = keys   + ((size_t)b * NN + tok0) * DD + 8 * g;
    const float* Vbase = values + ((size_t)b * NN + tok0) * DV + 8 * g;

    float u[8][8];
#pragma unroll
    for (int m = 0; m < 8; ++m)
#pragma unroll
        for (int j = 0; j < 8; ++j) u[m][j] = 0.f;
    float s_acc[8];
#pragma unroll
    for (int m = 0; m < 8; ++m) s_acc[m] = 0.f;

    // quad-buffered register batches (depth-3 prefetch)
    float4 kb0[4], kb1[4], vb0[4], vb1[4];
#pragma unroll
    for (int p = 0; p < 3; ++p) {
        const float4* kp = (const float4*)(Kbase + (size_t)(8 * p + t_sub) * DD);
        const float4* vp = (const float4*)(Vbase + (size_t)(8 * p + t_sub) * DV);
        kb0[p] = kp[0]; kb1[p] = kp[1]; vb0[p] = vp[0]; vb1[p] = vp[1];
    }

#pragma unroll
    for (int i = 0; i < NGROUP; ++i) {
        const int cur = i & 3;
        if (i + 3 < NGROUP) {
            const int nxt = (i + 3) & 3;
            const float4* kp = (const float4*)(Kbase + (size_t)(8 * (i + 3) + t_sub) * DD);
            const float4* vp = (const float4*)(Vbase + (size_t)(8 * (i + 3) + t_sub) * DV);
            kb0[nxt] = kp[0]; kb1[nxt] = kp[1]; vb0[nxt] = vp[0]; vb1[nxt] = vp[1];
        }

        const float4 kc0 = kb0[cur], kc1 = kb1[cur];
        float s[8];
#pragma unroll
        for (int m = 0; m < 8; ++m) {
            s[m] = kc0.x * q0[m].x + kc0.y * q0[m].y + kc0.z * q0[m].z + kc0.w * q0[m].w
                 + kc1.x * q1[m].x + kc1.y * q1[m].y + kc1.z * q1[m].z + kc1.w * q1[m].w;
        }
        // g-reduction entirely on VALU via DPP (no DS ops)
#pragma unroll
        for (int m = 0; m < 8; ++m) {
            s[m] = dpp_add<0xB1>(s[m]);   // + lane^1 (quad_perm 1,0,3,2)
            s[m] = dpp_add<0x4E>(s[m]);   // + lane^2 (quad_perm 2,3,0,1)
            s[m] = dpp_add<0x141>(s[m]);  // + lane^7 == xor4 (quad-uniform)
        }
        // softmax over m, in-register (no max-sub: scores ~N(0,1), fp32-safe)
        float e[8], sum = 0.f;
#pragma unroll
        for (int m = 0; m < 8; ++m) { e[m] = __expf(s[m]); sum += e[m]; }
        const float r = __builtin_amdgcn_rcpf(sum);
        const float4 vc0 = vb0[cur], vc1 = vb1[cur];
#pragma unroll
        for (int m = 0; m < 8; ++m) {
            const float a = e[m] * r + 1e-8f;
            s_acc[m] += a;
            u[m][0] += a * vc0.x; u[m][1] += a * vc0.y;
            u[m][2] += a * vc0.z; u[m][3] += a * vc0.w;
            u[m][4] += a * vc1.x; u[m][5] += a * vc1.y;
            u[m][6] += a * vc1.z; u[m][7] += a * vc1.w;
        }
    }

    // epilogue: reduce t_sub bits 0,1 (lane^8 via row_ror:8 — exact;
    // lane^16 via ds_swizzle); bit 2 via 16-half-partial LDS block reduce.
#pragma unroll
    for (int m = 0; m < 8; ++m) {
#pragma unroll
        for (int j = 0; j < 8; ++j) {
            u[m][j] = dpp_add<0x128>(u[m][j]);
            u[m][j] = swz16_add(u[m][j]);
        }
        s_acc[m] = dpp_add<0x128>(s_acc[m]);
        s_acc[m] = swz16_add(s_acc[m]);
    }

    __shared__ float lds[16 * 512];   // 8 waves x 2 halves
    __shared__ float lds_s[16 * 8];
    const int half = lane >> 5;
    if ((lane & 24) == 0) {  // lanes 0-7 and 32-39 hold the half-sums
        float* dst = lds + (wave * 2 + half) * 512 + 8 * g;
#pragma unroll
        for (int m = 0; m < 8; ++m) {
            float4 t0 = {u[m][0], u[m][1], u[m][2], u[m][3]};
            float4 t1 = {u[m][4], u[m][5], u[m][6], u[m][7]};
            *(float4*)(dst + m * 64)     = t0;
            *(float4*)(dst + m * 64 + 4) = t1;
        }
        if (g == 0) {
#pragma unroll
            for (int m = 0; m < 8; ++m) lds_s[(wave * 2 + half) * 8 + m] = s_acc[m];
        }
    }
    __syncthreads();

    float* pu = PU + ((size_t)b * CHUNKS + chnk) * 512;
    {
        float sum = 0.f;
#pragma unroll
        for (int k = 0; k < 16; ++k) sum += lds[k * 512 + tid];
        pu[tid] = sum;
    }
    if (tid < 8) {
        float ssum = 0.f;
#pragma unroll
        for (int k = 0; k < 16; ++k) ssum += lds_s[k * 8 + tid];
        PS[((size_t)b * CHUNKS + chnk) * 8 + tid] = ssum;
    }
}

// Stage 2: out[b][m][v] = (sum_c PU[b][c][m*64+v]) / (sum_c PS[b][c][m])
__global__ __launch_bounds__(512) void slot_attn_reduce(
    const float* __restrict__ PU, const float* __restrict__ PS,
    float* __restrict__ out)
{
    const int b = blockIdx.x;
    const int i = threadIdx.x;  // 0..511

    __shared__ float ssum[NQ];
    if (i < NQ) {
        float s = 0.f;
        const float* ps = PS + (size_t)b * CHUNKS * 8 + i;
#pragma unroll
        for (int c = 0; c < CHUNKS; ++c) s += ps[c * 8];
        ssum[i] = s;
    }
    __syncthreads();

    float usum = 0.f;
    const float* pu = PU + (size_t)b * CHUNKS * 512 + i;
#pragma unroll
    for (int c = 0; c < CHUNKS; ++c) usum += pu[c * 512];
    out[(size_t)b * 512 + i] = usum / ssum[i >> 6];
}

extern "C" void kernel_launch(void* const* d_in, const int* in_sizes, int n_in,
                              void* d_out, int out_size, void* d_ws, size_t ws_size,
                              hipStream_t stream) {
    const float* keys   = (const float*)d_in[0];
    const float* values = (const float*)d_in[1];
    const float* query  = (const float*)d_in[2];
    float* out = (float*)d_out;

    float* PU = (float*)d_ws;                       // BB*CHUNKS*512 floats (0.5 MB)
    float* PS = PU + (size_t)BB * CHUNKS * 512;     // BB*CHUNKS*8 floats

    slot_attn_partial<<<dim3(CHUNKS, BB), 512, 0, stream>>>(keys, values, query, PU, PS);
    slot_attn_reduce<<<dim3(BB), 512, 0, stream>>>(PU, PS, out);
}